// Round 10
// baseline (277.120 us; speedup 1.0000x reference)
//
#include <hip/hip_runtime.h>

// MobileMQA: B=8, C=256, H=W=64, NUM_HEADS=4, hd=64, ds=2
// R17: coop experiments closed (R14 proved the ~114us remainder is dispatch-
//      count-invariant harness overhead). k_fused rebuilt as 8-wave blocks:
//      wave-pairs (h, h+4-style) split the 32 KV windows 16/16 (flash KV-split)
//      -> 4 waves/SIMD (2x occupancy) at unchanged per-iteration MFMA density.
//      plds single-buffered (S->PV lag dropped; TLP covers it), Q-proj and WO
//      split 2x finer, O/den combined in f32 via LDS rounds. LDS 69.6KB,
//      __launch_bounds__(512,4) caps VGPR at 128 (demand ~120).
//      Preamble: proven R12/R16 chain unchanged.

#define CNT_INV (1.0f/1048576.0f)
#define EPSV 1e-5f
#define QSCALE 0.18033688f   // 0.125 * log2(e): folded into Q; exp = v_exp_f32(S)

// workspace layout (float offsets)
#define WS_STATS 0                    // 64
#define WS_XNT   64                   // bf16 xnT [b][n][c]  = 4,194,304 f
#define WS_XDS   4194368              // bf16 xdsT [b][m][c] = 1,048,576 f
#define WS_K     5242944              // bf16 k   [b][m][d]  = 262,144 f
#define WS_V     5505088              // bf16 v windows      = 262,144 f
#define WS_WQB   5767232              // bf16 wq  [o][c]     = 32,768 f
#define WS_WKV   5800000              // bf16 [wk;wv]        = 16,384 f
#define WS_WOB   5816384              // bf16 wo  [o][c]     = 32,768 f

typedef __attribute__((ext_vector_type(8))) short bf8_t;   // 8 bf16 MFMA A/B frag
typedef __attribute__((ext_vector_type(4))) float f4_t;    // MFMA C/D frag

static __device__ __forceinline__ unsigned fbits(float f) {
  union { float f; unsigned u; } v; v.f = f; return v.u;
}
static __device__ __forceinline__ unsigned short f2bf(float f) {  // RNE-ish
  unsigned u = fbits(f);
  return (unsigned short)((u + 0x7fffu + ((u >> 16) & 1u)) >> 16);
}
static __device__ __forceinline__ unsigned pk_rnd(float a, float b) {
  return __builtin_amdgcn_perm(fbits(b) + 0x8000u, fbits(a) + 0x8000u, 0x07060302u);
}
static __device__ __forceinline__ unsigned pk_tr(float a, float b) {
  return __builtin_amdgcn_perm(fbits(b), fbits(a), 0x07060302u);
}
static __device__ __forceinline__ float bf2f(unsigned short h) {
  union { unsigned u; float f; } v; v.u = ((unsigned)h) << 16; return v.f;
}
static __device__ __forceinline__ float fexp2(float x) {   // 2^x, raw v_exp_f32
  float r; asm("v_exp_f32 %0, %1" : "=v"(r) : "v"(x)); return r;
}

// ---------------- merged: weight prep (blocks >= 512) + stats (blocks < 512) ----------------
__global__ __launch_bounds__(256) void k_prep_stats(const float* __restrict__ x,
                                                    const float* __restrict__ wq,
                                                    const float* __restrict__ wk,
                                                    const float* __restrict__ wv,
                                                    const float* __restrict__ wo,
                                                    float* __restrict__ stats,
                                                    unsigned short* __restrict__ wqb,
                                                    unsigned short* __restrict__ wkvb,
                                                    unsigned short* __restrict__ wob) {
  const int blk = blockIdx.x;
  const int t = threadIdx.x;
  if (blk < 512) {
    const int b = blk >> 6;
    const int chunk = blk & 63;
    const float4* xb = (const float4*)(x + (size_t)b * 1048576 + (size_t)chunk * 16384);
    float s = 0.f, s2 = 0.f;
#pragma unroll
    for (int it = 0; it < 16; ++it) {
      float4 v = xb[it * 256 + t];
      s  += v.x + v.y + v.z + v.w;
      s2 += v.x * v.x + v.y * v.y + v.z * v.z + v.w * v.w;
    }
#pragma unroll
    for (int o = 32; o > 0; o >>= 1) {
      s  += __shfl_down(s, o);
      s2 += __shfl_down(s2, o);
    }
    __shared__ float red[8];
    const int wid = t >> 6;
    if ((t & 63) == 0) { red[wid] = s; red[4 + wid] = s2; }
    __syncthreads();
    if (t == 0) {
      atomicAdd(&stats[b * 2 + 0], red[0] + red[1] + red[2] + red[3]);
      atomicAdd(&stats[b * 2 + 1], red[4] + red[5] + red[6] + red[7]);
    }
  } else {
    const int idx = (blk - 512) * 256 + t;
    if (idx < 65536) wqb[idx] = f2bf(wq[idx]);
    else if (idx < 81920) wkvb[idx - 65536] = f2bf(wk[idx - 65536]);
    else if (idx < 98304) wkvb[idx - 65536] = f2bf(wv[idx - 81920]);
    else if (idx < 163840) wob[idx - 98304] = f2bf(wo[idx - 98304]);
  }
}

// ---------------- normalize + transpose + fused 2x2 pool (chunk-swizzled LDS) ----------------
__global__ __launch_bounds__(256) void k_xnt(const float* __restrict__ x,
                                             const float* __restrict__ gnw,
                                             const float* __restrict__ gnb,
                                             const float* __restrict__ stats,
                                             unsigned short* __restrict__ xnT,
                                             unsigned short* __restrict__ xdsT) {
  __shared__ unsigned short T[128][72];
  const int t = threadIdx.x;
  const int b = blockIdx.z, c0 = blockIdx.y * 64, hp = blockIdx.x;
  const int n0 = hp * 128;
  const float mu = stats[b * 2 + 0] * CNT_INV;
  const float rstd = rsqrtf(stats[b * 2 + 1] * CNT_INV - mu * mu + EPSV);
  const int n4 = (t & 31) * 4, cl = t >> 5;
  const int wswz = t & 7;
#pragma unroll
  for (int p = 0; p < 8; ++p) {
    const int c = c0 + p * 8 + cl;
    const float gw = gnw[c] * rstd;
    const float gb = gnb[c] - mu * rstd * gnw[c];
    const int pc = (p ^ wswz) * 8 + cl;
    float4 v = *(const float4*)&x[(size_t)(b * 256 + c) * 4096 + n0 + n4];
    T[n4 + 0][pc] = f2bf(v.x * gw + gb);
    T[n4 + 1][pc] = f2bf(v.y * gw + gb);
    T[n4 + 2][pc] = f2bf(v.z * gw + gb);
    T[n4 + 3][pc] = f2bf(v.w * gw + gb);
  }
  __syncthreads();
  {
    const int r = t >> 1, cb4 = (t & 1) * 4;
    const int rswz = (t >> 3) & 7;
    unsigned short* dst = xnT + ((size_t)b * 4096 + n0 + r) * 256 + c0 + cb4 * 8;
#pragma unroll
    for (int u = 0; u < 4; ++u)
      *(uint4*)(dst + u * 8) = *(const uint4*)&T[r][((cb4 + u) ^ rswz) * 8];
  }
  {
    const int wd = t >> 3, c8 = t & 7;
    const int pswz = (wd >> 1) & 7;
    const int pc = (c8 ^ pswz) * 8;
    uint4 u0 = *(const uint4*)&T[2 * wd][pc];
    uint4 u1 = *(const uint4*)&T[2 * wd + 1][pc];
    uint4 u2 = *(const uint4*)&T[64 + 2 * wd][pc];
    uint4 u3 = *(const uint4*)&T[64 + 2 * wd + 1][pc];
    const unsigned* p0 = (const unsigned*)&u0; const unsigned* p1 = (const unsigned*)&u1;
    const unsigned* p2 = (const unsigned*)&u2; const unsigned* p3 = (const unsigned*)&u3;
    unsigned outv[4];
#pragma unroll
    for (int i = 0; i < 4; ++i) {
      float lo = (bf2f((unsigned short)p0[i]) + bf2f((unsigned short)p1[i]) +
                  bf2f((unsigned short)p2[i]) + bf2f((unsigned short)p3[i])) * 0.25f;
      float hi = (bf2f((unsigned short)(p0[i] >> 16)) + bf2f((unsigned short)(p1[i] >> 16)) +
                  bf2f((unsigned short)(p2[i] >> 16)) + bf2f((unsigned short)(p3[i] >> 16))) * 0.25f;
      outv[i] = pk_rnd(lo, hi);
    }
    *(uint4*)(xdsT + ((size_t)b * 1024 + hp * 32 + wd) * 256 + c0 + c8 * 8) = *(uint4*)outv;
  }
}

// ---------------- K/V gemm: window-contiguous outputs for LDS staging ----------------
// kbf: [b][m][64 d], 16B d-chunk phys = logical ^ (m&7); vtbf: [b][win32][d64][m32]
__global__ __launch_bounds__(256) void k_gemm_kv(const unsigned short* __restrict__ wkvb,
                                                 const unsigned short* __restrict__ xdsT,
                                                 unsigned short* __restrict__ kbf,
                                                 unsigned short* __restrict__ vtbf) {
  __shared__ __align__(16) unsigned short kv[2][64][72];
  const int t = threadIdx.x;
  const int w = t >> 6, l = t & 63, lane16 = l & 15, quad = l >> 4;
  const int m0 = blockIdx.x * 64, b = blockIdx.y;
  const unsigned short* Abase = wkvb + (size_t)(w * 32 + lane16) * 256 + quad * 8;
  const unsigned short* Bbase = xdsT + ((size_t)b * 1024 + m0 + lane16) * 256 + quad * 8;
  f4_t acc[2][4];
#pragma unroll
  for (int i = 0; i < 2; ++i)
#pragma unroll
    for (int j = 0; j < 4; ++j) acc[i][j] = (f4_t){0.f, 0.f, 0.f, 0.f};
  for (int kc = 0; kc < 256; kc += 32) {
    bf8_t A[2], Bf[4];
#pragma unroll
    for (int og = 0; og < 2; ++og) A[og] = *(const bf8_t*)(Abase + (size_t)og * 16 * 256 + kc);
#pragma unroll
    for (int mg = 0; mg < 4; ++mg) Bf[mg] = *(const bf8_t*)(Bbase + (size_t)mg * 16 * 256 + kc);
#pragma unroll
    for (int og = 0; og < 2; ++og)
#pragma unroll
      for (int mg = 0; mg < 4; ++mg)
        acc[og][mg] = __builtin_amdgcn_mfma_f32_16x16x32_bf16(A[og], Bf[mg], acc[og][mg], 0, 0, 0);
  }
  if (w < 2) {
#pragma unroll
    for (int og = 0; og < 2; ++og)
#pragma unroll
      for (int mg = 0; mg < 4; ++mg) {
        uint2 p;
        p.x = pk_rnd(acc[og][mg][0], acc[og][mg][1]);
        p.y = pk_rnd(acc[og][mg][2], acc[og][mg][3]);
        *(uint2*)&kv[0][mg * 16 + lane16][w * 32 + og * 16 + quad * 4] = p;
      }
  } else {
#pragma unroll
    for (int og = 0; og < 2; ++og)
#pragma unroll
      for (int mg = 0; mg < 4; ++mg) {
        const int d0 = (w - 2) * 32 + og * 16 + quad * 4;
#pragma unroll
        for (int r = 0; r < 4; ++r)
          kv[1][d0 + r][mg * 16 + lane16] = f2bf(acc[og][mg][r]);
      }
  }
  __syncthreads();
  {
    const int row = t >> 2, q2 = t & 3;
    const int e = row & 7;
    uint4 k0 = *(const uint4*)&kv[0][row][q2 * 16];
    uint4 k1 = *(const uint4*)&kv[0][row][q2 * 16 + 8];
    unsigned short* kd = kbf + (size_t)b * 65536 + (size_t)(m0 + row) * 64;
    *(uint4*)(kd + ((q2 * 2) ^ e) * 8)     = k0;
    *(uint4*)(kd + ((q2 * 2 + 1) ^ e) * 8) = k1;
    uint4 v0 = *(const uint4*)&kv[1][row][q2 * 16];
    uint4 v1 = *(const uint4*)&kv[1][row][q2 * 16 + 8];
    unsigned short* vd = vtbf + (size_t)b * 65536 + (size_t)(blockIdx.x * 2 + (q2 >> 1)) * 2048 +
                         (size_t)row * 32 + (q2 & 1) * 16;
    *(uint4*)vd = v0; *(uint4*)(vd + 8) = v1;
  }
}

// ---------------- fused Q-proj + attention + WO + residual (8 waves, KV-split) ----------------
// block = (b, 64-n tile), 512 threads. wave w: head h = w&3, KV group kvg = w>>2.
// Group kvg handles windows kvg*16 .. kvg*16+15; O/den combined in f32 via LDS.
// LDS (69,632 B): smem[18432] u16 = qst(4x[64][72]) -> plds(8x[64][36]) -> aos[64][264] union;
//                 kstA[2][2][2048] + vstA[2][2][2048] staging dbuf per group (fcomb alias).
__global__ __launch_bounds__(512, 4) void k_fused(const unsigned short* __restrict__ wqb,
                                                  const unsigned short* __restrict__ xnT,
                                                  const unsigned short* __restrict__ kbf,
                                                  const unsigned short* __restrict__ vtbf,
                                                  const unsigned short* __restrict__ wob,
                                                  const float* __restrict__ x,
                                                  const float* __restrict__ gamma,
                                                  float* __restrict__ outp) {
  __shared__ __align__(16) unsigned short smem[18432];        // 36,864 B
  __shared__ __align__(16) unsigned short kstA[2][2][2048];   // 16,384 B
  __shared__ __align__(16) unsigned short vstA[2][2][2048];   // 16,384 B
  const int t = threadIdx.x;
  const int w = t >> 6, l = t & 63, lane16 = l & 15, quad = l >> 4;
  const int h = w & 3, kvg = w >> 2;
  const int n0 = blockIdx.x * 64, b = blockIdx.y;
  unsigned short* qst = smem + h * 4608;                                // [64][72] per head
  unsigned short (*plds)[36] = (unsigned short (*)[36])(smem + w * 2304);  // [64][36] per wave
  unsigned short (*aos)[264] = (unsigned short (*)[264])smem;

  const unsigned short* kb = kbf + (size_t)b * 65536;
  const unsigned short* vb = vtbf + (size_t)b * 65536;

  // ---- Phase 1: Q-proj — wave pair (h,kvg) splits ng: this wave does ng = kvg*2 + {0,1} ----
  {
    const unsigned short* Abase = wqb + (size_t)(h * 64 + lane16) * 256 + quad * 8;
    const unsigned short* Bbase = xnT + ((size_t)b * 4096 + n0 + kvg * 32 + lane16) * 256 + quad * 8;
    f4_t qacc[4][2];
#pragma unroll
    for (int i = 0; i < 4; ++i)
#pragma unroll
      for (int j = 0; j < 2; ++j) qacc[i][j] = (f4_t){0.f, 0.f, 0.f, 0.f};
    for (int kc = 0; kc < 256; kc += 32) {
      bf8_t A[4], Bf[2];
#pragma unroll
      for (int og = 0; og < 4; ++og) A[og] = *(const bf8_t*)(Abase + (size_t)og * 16 * 256 + kc);
#pragma unroll
      for (int j = 0; j < 2; ++j) Bf[j] = *(const bf8_t*)(Bbase + (size_t)j * 16 * 256 + kc);
#pragma unroll
      for (int og = 0; og < 4; ++og)
#pragma unroll
        for (int j = 0; j < 2; ++j)
          qacc[og][j] = __builtin_amdgcn_mfma_f32_16x16x32_bf16(A[og], Bf[j], qacc[og][j], 0, 0, 0);
    }
    // C-layout (row d = og*16+quad*4+r, col q = ng*16+lane16) -> qst[q][d]
#pragma unroll
    for (int og = 0; og < 4; ++og)
#pragma unroll
      for (int j = 0; j < 2; ++j) {
        const int ng = kvg * 2 + j;
        uint2 p;
        p.x = pk_rnd(qacc[og][j][0] * QSCALE, qacc[og][j][1] * QSCALE);
        p.y = pk_rnd(qacc[og][j][2] * QSCALE, qacc[og][j][3] * QSCALE);
        *(uint2*)&qst[(ng * 16 + lane16) * 72 + og * 16 + quad * 4] = p;
      }
  }
  __syncthreads();   // pair-written qst complete
  bf8_t Qf[4][2];
#pragma unroll
  for (int qg = 0; qg < 4; ++qg)
#pragma unroll
    for (int dc = 0; dc < 2; ++dc)
      Qf[qg][dc] = *(const bf8_t*)&qst[(qg * 16 + lane16) * 72 + dc * 32 + quad * 8];

  // ---- KV staging roles within the 4-wave group ----
  const int wr = w & 3, sw = wr & 1;
  const unsigned short* sbase = (wr < 2) ? kb : vb;
  unsigned short* sdst0 = ((wr < 2) ? &kstA[kvg][0][0] : &vstA[kvg][0][0]) + sw * 1024 + l * 8;
  unsigned short* sdst1 = ((wr < 2) ? &kstA[kvg][1][0] : &vstA[kvg][1][0]) + sw * 1024 + l * 8;

#define STAGE_ISSUE(WIN, R0, R1)                                              \
  { const unsigned short* sp = sbase + (size_t)(WIN) * 2048 + sw * 1024 + l * 8; \
    R0 = *(const uint4*)sp; R1 = *(const uint4*)(sp + 512); }
#define STAGE_WRITE(DP, R0, R1)                                               \
  { *(uint4*)(DP) = R0; *(uint4*)((DP) + 512) = R1; }
#define READ_K(BUF, KREG)                                                     \
  {                                                                           \
    _Pragma("unroll")                                                         \
    for (int s = 0; s < 2; ++s) {                                             \
      _Pragma("unroll")                                                       \
      for (int dc = 0; dc < 2; ++dc)                                          \
        KREG[s][dc] = *(const bf8_t*)&kstA[kvg][BUF][(s * 16 + lane16) * 64 + \
                                              (((dc * 4 + quad) ^ (lane16 & 7)) * 8)]; \
    }                                                                         \
  }
#define READ_V(BUF, VREG)                                                     \
  {                                                                           \
    _Pragma("unroll")                                                         \
    for (int dg = 0; dg < 4; ++dg)                                            \
      VREG[dg] = *(const bf8_t*)&vstA[kvg][BUF][(dg * 16 + lane16) * 32 + quad * 8]; \
  }

  // prologue: stage this group's window 0 into buf0 (plds not yet touched)
  {
    uint4 a0, a1;
    STAGE_ISSUE(kvg * 16, a0, a1);
    STAGE_WRITE(sdst0, a0, a1);
  }
  __syncthreads();   // qst reads done (Qf in regs) + buf0 ready -> plds may be overwritten

  // ---- Phase 2: attention over this group's 16 windows ----
  f4_t O[4][4];
#pragma unroll
  for (int dg = 0; dg < 4; ++dg)
#pragma unroll
    for (int qg = 0; qg < 4; ++qg) O[dg][qg] = (f4_t){0.f, 0.f, 0.f, 0.f};
  f4_t O4[4];
#pragma unroll
  for (int qg = 0; qg < 4; ++qg) O4[qg] = (f4_t){0.f, 0.f, 0.f, 0.f};
  const short onebf = (lane16 == 0) ? (short)0x3F80 : (short)0;
  const bf8_t Aone = {onebf, onebf, onebf, onebf, onebf, onebf, onebf, onebf};

  for (int it = 0; it < 16; ++it) {
    const int cur = it & 1;
    uint4 g0, g1;
    if (it < 15) STAGE_ISSUE(kvg * 16 + it + 1, g0, g1);
    bf8_t Kc[2][2];
    READ_K(cur, Kc);
    // S = K.Q -> exp -> pack -> plds (single-buffer, same-wave in-order DS)
#pragma unroll
    for (int qg = 0; qg < 4; ++qg) {
#pragma unroll
      for (int s = 0; s < 2; ++s) {
        f4_t S = (f4_t){0.f, 0.f, 0.f, 0.f};
        S = __builtin_amdgcn_mfma_f32_16x16x32_bf16(Kc[s][0], Qf[qg][0], S, 0, 0, 0);
        S = __builtin_amdgcn_mfma_f32_16x16x32_bf16(Kc[s][1], Qf[qg][1], S, 0, 0, 0);
        float e0 = fexp2(S[0]);
        float e1 = fexp2(S[1]);
        float e2 = fexp2(S[2]);
        float e3 = fexp2(S[3]);
        uint2 p; p.x = pk_tr(e0, e1); p.y = pk_tr(e2, e3);
        *(uint2*)&plds[qg * 16 + lane16][s * 16 + quad * 4] = p;
      }
    }
    bf8_t Vc[4];
    READ_V(cur, Vc);
    bf8_t Pf[4];
#pragma unroll
    for (int qg = 0; qg < 4; ++qg)
      Pf[qg] = *(const bf8_t*)&plds[qg * 16 + lane16][quad * 8];
    __builtin_amdgcn_s_setprio(1);
#pragma unroll
    for (int dg = 0; dg < 4; ++dg)
#pragma unroll
      for (int qg = 0; qg < 4; ++qg)
        O[dg][qg] = __builtin_amdgcn_mfma_f32_16x16x32_bf16(Vc[dg], Pf[qg], O[dg][qg], 0, 0, 0);
#pragma unroll
    for (int qg = 0; qg < 4; ++qg)
      O4[qg] = __builtin_amdgcn_mfma_f32_16x16x32_bf16(Aone, Pf[qg], O4[qg], 0, 0, 0);
    __builtin_amdgcn_s_setprio(0);
    if (it < 15) STAGE_WRITE((cur ? sdst0 : sdst1), g0, g1);   // write buf cur^1
    __syncthreads();
  }
#undef STAGE_ISSUE
#undef STAGE_WRITE
#undef READ_K
#undef READ_V

  // ---- combine: kvg1 partial O (4 rounds of one dg) + den round, f32 via kstA region ----
  float* fcomb = (float*)&kstA[0][0][0];   // 16,384 B = 4096 floats = one round
#pragma unroll
  for (int dgr = 0; dgr < 4; ++dgr) {
    if (kvg == 1) {
#pragma unroll
      for (int qg = 0; qg < 4; ++qg)
#pragma unroll
        for (int rr = 0; rr < 4; ++rr)
          fcomb[(qg * 4 + rr) * 256 + h * 64 + l] = O[dgr][qg][rr];
    }
    __syncthreads();
    if (kvg == 0) {
#pragma unroll
      for (int qg = 0; qg < 4; ++qg)
#pragma unroll
        for (int rr = 0; rr < 4; ++rr)
          O[dgr][qg][rr] += fcomb[(qg * 4 + rr) * 256 + h * 64 + l];
    }
    __syncthreads();
  }
  if (kvg == 1) {
#pragma unroll
    for (int qg = 0; qg < 4; ++qg)
#pragma unroll
      for (int rr = 0; rr < 4; ++rr)
        fcomb[(qg * 4 + rr) * 256 + h * 64 + l] = O4[qg][rr];
  }
  __syncthreads();
  if (kvg == 0) {
#pragma unroll
    for (int qg = 0; qg < 4; ++qg)
#pragma unroll
      for (int rr = 0; rr < 4; ++rr)
        O4[qg][rr] += fcomb[(qg * 4 + rr) * 256 + h * 64 + l];
  }
  __syncthreads();

  // ---- kvg0: rden + aos write (rows n, cols c = h*64 + d) ----
  if (kvg == 0) {
    float rden[4];
#pragma unroll
    for (int qg = 0; qg < 4; ++qg) {
      float d = __shfl(O4[qg][0], lane16);
      rden[qg] = 1.f / d;
    }
#pragma unroll
    for (int dg = 0; dg < 4; ++dg)
#pragma unroll
      for (int qg = 0; qg < 4; ++qg) {
        const int c0 = h * 64 + dg * 16 + quad * 4;
        uint2 p;
        p.x = pk_rnd(O[dg][qg][0] * rden[qg], O[dg][qg][1] * rden[qg]);
        p.y = pk_rnd(O[dg][qg][2] * rden[qg], O[dg][qg][3] * rden[qg]);
        *(uint2*)&aos[qg * 16 + lane16][c0] = p;
      }
  }
  __syncthreads();

  // ---- Phase 3: WO gemm from LDS + residual — 8 waves, 32 o-rows each ----
  {
    const unsigned short* Wbase = wob + (size_t)(w * 32 + lane16) * 256 + quad * 8;
    f4_t acc[2][4];
#pragma unroll
    for (int i = 0; i < 2; ++i)
#pragma unroll
      for (int j = 0; j < 4; ++j) acc[i][j] = (f4_t){0.f, 0.f, 0.f, 0.f};
    for (int kc = 0; kc < 256; kc += 32) {
      bf8_t A[2], Bf[4];
#pragma unroll
      for (int og = 0; og < 2; ++og) A[og] = *(const bf8_t*)(Wbase + (size_t)og * 16 * 256 + kc);
#pragma unroll
      for (int ng = 0; ng < 4; ++ng) Bf[ng] = *(const bf8_t*)&aos[ng * 16 + lane16][kc + quad * 8];
#pragma unroll
      for (int og = 0; og < 2; ++og)
#pragma unroll
        for (int ng = 0; ng < 4; ++ng)
          acc[og][ng] = __builtin_amdgcn_mfma_f32_16x16x32_bf16(A[og], Bf[ng], acc[og][ng], 0, 0, 0);
    }
#pragma unroll
    for (int og = 0; og < 2; ++og) {
      float4 g4 = *(const float4*)&gamma[w * 32 + og * 16 + quad * 4];
      const float g[4] = {g4.x, g4.y, g4.z, g4.w};
#pragma unroll
      for (int ng = 0; ng < 4; ++ng) {
        const int n = n0 + ng * 16 + lane16;
#pragma unroll
        for (int r = 0; r < 4; ++r) {
          const int o = w * 32 + og * 16 + quad * 4 + r;
          const size_t ix = ((size_t)(b * 256 + o)) * 4096 + n;
          outp[ix] = x[ix] + g[r] * acc[og][ng][r];
        }
      }
    }
  }
}

extern "C" void kernel_launch(void* const* d_in, const int* in_sizes, int n_in,
                              void* d_out, int out_size, void* d_ws, size_t ws_size,
                              hipStream_t stream) {
  const float* x     = (const float*)d_in[0];
  const float* gnw   = (const float*)d_in[1];
  const float* gnb   = (const float*)d_in[2];
  const float* wq    = (const float*)d_in[3];
  const float* wk    = (const float*)d_in[4];
  const float* wv    = (const float*)d_in[5];
  const float* wo    = (const float*)d_in[6];
  const float* gamma = (const float*)d_in[7];
  float* out = (float*)d_out;
  float* ws  = (float*)d_ws;
  unsigned short* xnT  = (unsigned short*)(ws + WS_XNT);
  unsigned short* xdsT = (unsigned short*)(ws + WS_XDS);
  unsigned short* kbf  = (unsigned short*)(ws + WS_K);
  unsigned short* vtbf = (unsigned short*)(ws + WS_V);
  unsigned short* wqb  = (unsigned short*)(ws + WS_WQB);
  unsigned short* wkvb = (unsigned short*)(ws + WS_WKV);
  unsigned short* wob  = (unsigned short*)(ws + WS_WOB);

  hipMemsetAsync(ws, 0, 256, stream);
  k_prep_stats<<<1152, 256, 0, stream>>>(x, wq, wk, wv, wo, ws + WS_STATS, wqb, wkvb, wob);
  k_xnt<<<dim3(32, 4, 8), 256, 0, stream>>>(x, gnw, gnb, ws + WS_STATS, xnT, xdsT);
  k_gemm_kv<<<dim3(16, 8), 256, 0, stream>>>(wkvb, xdsT, kbf, vtbf);
  k_fused<<<dim3(64, 8), 512, 0, stream>>>(wqb, xnT, kbf, vtbf, wob, x, gamma, out);
}